// Round 1
// baseline (59.741 us; speedup 1.0000x reference)
//
#include <hip/hip_runtime.h>
#include <hip/hip_bf16.h>

// Closed-form reduction:
//   s = A @ x  (A: [5000,20], x: [20])
//   loss = sum_{i,j} (s_i - b_j)^2
//        = N * sum(s^2) - 2 * sum(s) * sum(b) + N * sum(b^2),  N = 5000
//
// Kernel 1: per-block partial sums (S1=Σs, S2=Σs², B1=Σb, B2=Σb²) -> d_ws
// Kernel 2: reduce partials, emit scalar.

#define N_ROWS 5000
#define N_FEAT 20
#define NBLK   20
#define BLKSZ  256

__device__ __forceinline__ double wave_reduce_sum(double v) {
    #pragma unroll
    for (int off = 32; off > 0; off >>= 1)
        v += __shfl_down(v, off, 64);
    return v;
}

__global__ __launch_bounds__(BLKSZ) void lsq_partial_kernel(
        const float* __restrict__ A, const float* __restrict__ b,
        const float* __restrict__ x, double* __restrict__ ws) {
    __shared__ float xs[N_FEAT];
    if (threadIdx.x < N_FEAT) xs[threadIdx.x] = x[threadIdx.x];
    __syncthreads();

    double s1 = 0.0, s2 = 0.0, b1 = 0.0, b2 = 0.0;
    for (int i = blockIdx.x * BLKSZ + threadIdx.x; i < N_ROWS;
         i += NBLK * BLKSZ) {
        const float* __restrict__ row = A + (long)i * N_FEAT;
        float s = 0.0f;
        #pragma unroll
        for (int k = 0; k < N_FEAT; ++k) s += row[k] * xs[k];
        s1 += (double)s;
        s2 += (double)s * (double)s;
        float bv = b[i];
        b1 += (double)bv;
        b2 += (double)bv * (double)bv;
    }

    // wave reduce (wave64), then LDS across the 4 waves
    s1 = wave_reduce_sum(s1);
    s2 = wave_reduce_sum(s2);
    b1 = wave_reduce_sum(b1);
    b2 = wave_reduce_sum(b2);

    __shared__ double red[4][4];
    int lane = threadIdx.x & 63;
    int wave = threadIdx.x >> 6;
    if (lane == 0) {
        red[wave][0] = s1; red[wave][1] = s2;
        red[wave][2] = b1; red[wave][3] = b2;
    }
    __syncthreads();
    if (threadIdx.x == 0) {
        double t0 = 0, t1 = 0, t2 = 0, t3 = 0;
        #pragma unroll
        for (int w = 0; w < 4; ++w) {
            t0 += red[w][0]; t1 += red[w][1];
            t2 += red[w][2]; t3 += red[w][3];
        }
        double* p = ws + 4 * blockIdx.x;
        p[0] = t0; p[1] = t1; p[2] = t2; p[3] = t3;
    }
}

__global__ __launch_bounds__(64) void lsq_finalize_kernel(
        const double* __restrict__ ws, float* __restrict__ out) {
    double s1 = 0, s2 = 0, b1 = 0, b2 = 0;
    if (threadIdx.x < NBLK) {
        const double* p = ws + 4 * threadIdx.x;
        s1 = p[0]; s2 = p[1]; b1 = p[2]; b2 = p[3];
    }
    s1 = wave_reduce_sum(s1);
    s2 = wave_reduce_sum(s2);
    b1 = wave_reduce_sum(b1);
    b2 = wave_reduce_sum(b2);
    if (threadIdx.x == 0) {
        double n = (double)N_ROWS;
        out[0] = (float)(n * s2 - 2.0 * s1 * b1 + n * b2);
    }
}

extern "C" void kernel_launch(void* const* d_in, const int* in_sizes, int n_in,
                              void* d_out, int out_size, void* d_ws, size_t ws_size,
                              hipStream_t stream) {
    const float* A = (const float*)d_in[0];   // [5000,20]
    const float* b = (const float*)d_in[1];   // [5000]
    const float* x = (const float*)d_in[2];   // [20]
    float* out = (float*)d_out;
    double* ws = (double*)d_ws;               // 20 blocks * 4 doubles = 640 B

    lsq_partial_kernel<<<NBLK, BLKSZ, 0, stream>>>(A, b, x, ws);
    lsq_finalize_kernel<<<1, 64, 0, stream>>>(ws, out);
}